// Round 1
// baseline (633.933 us; speedup 1.0000x reference)
//
#include <hip/hip_runtime.h>

// RoutingCapsule: B=32, N_in=2048, N_out=64, D_out=32, D_in=16
// Strategy: never materialize u_hat (512MB); re-stream W (256MB) per pass.
// Each (i,j) micro-matmul = one v_mfma_f32_32x32x16_bf16 (d x b, K=p=16).
//   s[b,j,d] = sum_i c[b,i,j]*u_hat[b,i,j,d]  -> MFMA accumulate, c folded into B-operand
//   t[b,i,j] = sum_d u_hat[b,i,j,d]*v[b,j,d]  -> MFMA (acc=0) then contract C-frag with v regs
// b_log linearity: iter2 logits = u_hat . (v0+v1)  -> only vsum stored.
// ws usage: t/c buffer 16MB + s 256KB + v0T 256KB + vsumT 256KB  (~16.75MB)

#define B_   32
#define NI   2048
#define NO   64
#define DO_  32
#define DI   16
#define IC   64            // i's per wave task
#define NCHUNK (NI / IC)   // 32
#define NWAVE (NO * NCHUNK) // 2048 wave tasks -> 512 blocks x 256 thr

typedef __bf16 bf16x8 __attribute__((ext_vector_type(8)));
typedef float  f32x16 __attribute__((ext_vector_type(16)));

// ---------------- s-pass: s[j][d][b] += sum_{i in chunk} c*.W.x via MFMA ----------------
__global__ __launch_bounds__(256) void s_mfma_kernel(const float* __restrict__ W,
                                                     const float* __restrict__ x,
                                                     const float* __restrict__ c,
                                                     float* __restrict__ s)
{
    const int tid  = threadIdx.x;
    const int lane = tid & 63;
    const int wid  = blockIdx.x * 4 + (tid >> 6);   // 0..2047
    const int j    = wid & 63;
    const int i0   = (wid >> 6) * IC;
    const int m    = lane & 31;    // A-row (d) and B-col (b)
    const int h    = lane >> 5;    // k-half: k = 8h+e

    const float* Wp = W + (((size_t)i0 * NO + j) * DO_ + m) * DI + 8 * h;
    const float* xp = x + ((size_t)m * NI + i0) * DI + 8 * h;
    const bool hasC = (c != nullptr);
    const float cunif = 1.0f / 64.0f;

    f32x16 acc;
    #pragma unroll
    for (int r = 0; r < 16; ++r) acc[r] = 0.0f;

    #pragma unroll 4
    for (int ii = 0; ii < IC; ++ii) {
        const float4 w0 = ((const float4*)Wp)[0];
        const float4 w1 = ((const float4*)Wp)[1];
        const float4 x0 = ((const float4*)xp)[0];
        const float4 x1 = ((const float4*)xp)[1];
        float cv = cunif;
        if (hasC) cv = c[(size_t)(i0 + ii) * (NO * B_) + j * B_ + m];

        bf16x8 af, bv;
        af[0] = (__bf16)w0.x; af[1] = (__bf16)w0.y; af[2] = (__bf16)w0.z; af[3] = (__bf16)w0.w;
        af[4] = (__bf16)w1.x; af[5] = (__bf16)w1.y; af[6] = (__bf16)w1.z; af[7] = (__bf16)w1.w;
        bv[0] = (__bf16)(cv * x0.x); bv[1] = (__bf16)(cv * x0.y);
        bv[2] = (__bf16)(cv * x0.z); bv[3] = (__bf16)(cv * x0.w);
        bv[4] = (__bf16)(cv * x1.x); bv[5] = (__bf16)(cv * x1.y);
        bv[6] = (__bf16)(cv * x1.z); bv[7] = (__bf16)(cv * x1.w);

        acc = __builtin_amdgcn_mfma_f32_32x32x16_bf16(af, bv, acc, 0, 0, 0);

        Wp += (size_t)NO * DO_ * DI;  // next i
        xp += DI;
    }

    // C/D layout (m74/m101): col=lane&31, row=(r&3)+8*(r>>2)+4*(lane>>5)
    #pragma unroll
    for (int r = 0; r < 16; ++r) {
        const int row = (r & 3) + 8 * (r >> 2) + 4 * h;
        atomicAdd(&s[((size_t)j * DO_ + row) * B_ + m], acc[r]);
    }
}

// ---------------- t-pass: t[i][j][b] = sum_d u_hat[d][b] * vT[j][d][b] ----------------
__global__ __launch_bounds__(256) void t_mfma_kernel(const float* __restrict__ W,
                                                     const float* __restrict__ x,
                                                     const float* __restrict__ vT,
                                                     float* __restrict__ t)
{
    const int tid  = threadIdx.x;
    const int lane = tid & 63;
    const int wid  = blockIdx.x * 4 + (tid >> 6);
    const int j    = wid & 63;
    const int i0   = (wid >> 6) * IC;
    const int m    = lane & 31;
    const int h    = lane >> 5;

    const float* Wp = W + (((size_t)i0 * NO + j) * DO_ + m) * DI + 8 * h;
    const float* xp = x + ((size_t)m * NI + i0) * DI + 8 * h;

    float vr[16];
    #pragma unroll
    for (int r = 0; r < 16; ++r) {
        const int row = (r & 3) + 8 * (r >> 2) + 4 * h;
        vr[r] = vT[((size_t)j * DO_ + row) * B_ + m];
    }

    #pragma unroll 2
    for (int ii = 0; ii < IC; ++ii) {
        const float4 w0 = ((const float4*)Wp)[0];
        const float4 w1 = ((const float4*)Wp)[1];
        const float4 x0 = ((const float4*)xp)[0];
        const float4 x1 = ((const float4*)xp)[1];

        bf16x8 af, bv;
        af[0] = (__bf16)w0.x; af[1] = (__bf16)w0.y; af[2] = (__bf16)w0.z; af[3] = (__bf16)w0.w;
        af[4] = (__bf16)w1.x; af[5] = (__bf16)w1.y; af[6] = (__bf16)w1.z; af[7] = (__bf16)w1.w;
        bv[0] = (__bf16)x0.x; bv[1] = (__bf16)x0.y; bv[2] = (__bf16)x0.z; bv[3] = (__bf16)x0.w;
        bv[4] = (__bf16)x1.x; bv[5] = (__bf16)x1.y; bv[6] = (__bf16)x1.z; bv[7] = (__bf16)x1.w;

        f32x16 z;
        #pragma unroll
        for (int r = 0; r < 16; ++r) z[r] = 0.0f;
        f32x16 u = __builtin_amdgcn_mfma_f32_32x32x16_bf16(af, bv, z, 0, 0, 0);

        // contract with v over d (rows); 4 partial chains for ILP
        float p0 = 0.f, p1 = 0.f, p2 = 0.f, p3 = 0.f;
        #pragma unroll
        for (int r = 0; r < 16; r += 4) {
            p0 = fmaf(u[r + 0], vr[r + 0], p0);
            p1 = fmaf(u[r + 1], vr[r + 1], p1);
            p2 = fmaf(u[r + 2], vr[r + 2], p2);
            p3 = fmaf(u[r + 3], vr[r + 3], p3);
        }
        float tp = (p0 + p1) + (p2 + p3);
        tp += __shfl_xor(tp, 32);   // combine row-halves (lane l and l^32 share b)
        if (h == 0) t[(size_t)(i0 + ii) * (NO * B_) + j * B_ + m] = tp;

        Wp += (size_t)NO * DO_ * DI;
        xp += DI;
    }
}

// ---------------- softmax over j, per (i): t[i][j][b] -> c[i][j][b] in-place ----------------
__global__ __launch_bounds__(256) void softmax_kernel(float* __restrict__ t)
{
    __shared__ float red[8][32];
    __shared__ float row_m[32];
    __shared__ float row_s[32];
    const int i = blockIdx.x;
    const int tid = threadIdx.x;
    const int b = tid & 31;
    const int g = tid >> 5;            // 0..7, owns j = g*8 .. g*8+7
    float* base = t + (size_t)i * (NO * B_);

    float tv[8];
    #pragma unroll
    for (int k = 0; k < 8; ++k) tv[k] = base[(g * 8 + k) * B_ + b];

    float m8 = tv[0];
    #pragma unroll
    for (int k = 1; k < 8; ++k) m8 = fmaxf(m8, tv[k]);
    red[g][b] = m8;
    __syncthreads();
    if (tid < 32) {
        float mm = red[0][tid];
        #pragma unroll
        for (int gg = 1; gg < 8; ++gg) mm = fmaxf(mm, red[gg][tid]);
        row_m[tid] = mm;
    }
    __syncthreads();
    const float mm = row_m[b];
    float e[8]; float ps = 0.f;
    #pragma unroll
    for (int k = 0; k < 8; ++k) { e[k] = __expf(tv[k] - mm); ps += e[k]; }
    __syncthreads();
    red[g][b] = ps;
    __syncthreads();
    if (tid < 32) {
        float ss = 0.f;
        #pragma unroll
        for (int gg = 0; gg < 8; ++gg) ss += red[gg][tid];
        row_s[tid] = 1.0f / ss;
    }
    __syncthreads();
    const float inv = row_s[b];
    #pragma unroll
    for (int k = 0; k < 8; ++k) base[(g * 8 + k) * B_ + b] = e[k] * inv;
}

// ---------------- squash: v = squash(s+bias); modes for v0 / vsum / final out ----------------
// mode 0: out[j][d][b] = v                 (v0T)
// mode 1: out[j][d][b] = v0T + v           (vsumT)
// mode 2: out[b][j][d] = v                 (d_out, reference layout)
__global__ __launch_bounds__(256) void squash_kernel(const float* __restrict__ s,
                                                     const float* __restrict__ bias,
                                                     const float* __restrict__ v0T,
                                                     float* __restrict__ out,
                                                     int mode)
{
    __shared__ float red[8][32];
    __shared__ float scl[32];
    const int j = blockIdx.x;
    const int tid = threadIdx.x;
    const int b = tid & 31;
    const int g = tid >> 5;
    const int d0 = g * 4;

    float sv[4];
    #pragma unroll
    for (int q = 0; q < 4; ++q)
        sv[q] = s[((size_t)j * DO_ + d0 + q) * B_ + b] + bias[j * DO_ + d0 + q];

    float p = 0.f;
    #pragma unroll
    for (int q = 0; q < 4; ++q) p = fmaf(sv[q], sv[q], p);
    red[g][b] = p;
    __syncthreads();
    if (tid < 32) {
        float n2 = 0.f;
        #pragma unroll
        for (int gg = 0; gg < 8; ++gg) n2 += red[gg][tid];
        scl[tid] = n2 / ((1.0f + n2) * sqrtf(n2 + 1e-7f));
    }
    __syncthreads();
    const float sc = scl[b];
    #pragma unroll
    for (int q = 0; q < 4; ++q) {
        const int d = d0 + q;
        const float vq = sv[q] * sc;
        if (mode == 0)      out[((size_t)j * DO_ + d) * B_ + b] = vq;
        else if (mode == 1) out[((size_t)j * DO_ + d) * B_ + b] =
                                v0T[((size_t)j * DO_ + d) * B_ + b] + vq;
        else                out[((size_t)b * NO + j) * DO_ + d] = vq;
    }
}

extern "C" void kernel_launch(void* const* d_in, const int* in_sizes, int n_in,
                              void* d_out, int out_size, void* d_ws, size_t ws_size,
                              hipStream_t stream)
{
    const float* x    = (const float*)d_in[0];   // [32][2048][16]
    const float* W    = (const float*)d_in[1];   // [2048][64][32][16]
    const float* bias = (const float*)d_in[2];   // [64][32]
    float* out = (float*)d_out;                  // [32][64][32]

    float* t_buf = (float*)d_ws;                         // NI*NO*B = 4M floats (16MB)
    float* s_buf = t_buf + (size_t)NI * NO * B_;         // 64K floats
    float* v0T   = s_buf + (size_t)NO * DO_ * B_;        // 64K floats
    float* vsT   = v0T  + (size_t)NO * DO_ * B_;         // 64K floats

    const dim3 gW(NWAVE / 4), tW(256);
    const dim3 gSm(NI), gSq(NO);
    const size_t sBytes = (size_t)NO * DO_ * B_ * sizeof(float);

    // ---- iter 0: c uniform -> s0 -> v0
    hipMemsetAsync(s_buf, 0, sBytes, stream);
    s_mfma_kernel<<<gW, tW, 0, stream>>>(W, x, nullptr, s_buf);
    squash_kernel<<<gSq, tW, 0, stream>>>(s_buf, bias, nullptr, v0T, 0);

    // ---- iter 1: t = u.v0 ; c = softmax(t) ; s1 ; vsum = v0 + v1
    t_mfma_kernel<<<gW, tW, 0, stream>>>(W, x, v0T, t_buf);
    softmax_kernel<<<gSm, tW, 0, stream>>>(t_buf);
    hipMemsetAsync(s_buf, 0, sBytes, stream);
    s_mfma_kernel<<<gW, tW, 0, stream>>>(W, x, t_buf, s_buf);
    squash_kernel<<<gSq, tW, 0, stream>>>(s_buf, bias, v0T, vsT, 1);

    // ---- iter 2: logits = u.(v0+v1) ; c = softmax ; s2 ; out = squash(s2)
    t_mfma_kernel<<<gW, tW, 0, stream>>>(W, x, vsT, t_buf);
    softmax_kernel<<<gSm, tW, 0, stream>>>(t_buf);
    hipMemsetAsync(s_buf, 0, sBytes, stream);
    s_mfma_kernel<<<gW, tW, 0, stream>>>(W, x, t_buf, s_buf);
    squash_kernel<<<gSq, tW, 0, stream>>>(s_buf, bias, nullptr, out, 2);
}

// Round 2
// 543.174 us; speedup vs baseline: 1.1671x; 1.1671x over previous
//
#include <hip/hip_runtime.h>

// RoutingCapsule: B=32, N_in=2048, N_out=64, D_out=32, D_in=16
// R2 structure:
//   convert_x:  x fp32 -> xb bf16 (2 MB)
//   pass A:     stream W fp32 once; write Wb bf16 (128 MB) + accumulate s0 (uniform c)
//   t-pass x2:  logits t[i][j][b] = u_hat . v   (streams Wb 128 MB)
//   s-pass x2:  s partials = sum_i c*u_hat      (streams Wb 128 MB, c post-MFMA FMA)
//   softmax x2, squash x3 (squash also reduces the 32-chunk partial buffer)
// Per-pass parallelism: 8192 wave-tasks (IC=16) = 2048 blocks -> 32 waves/CU.
// No atomics: block (4 waves, same j) LDS-reduces -> partial[32][64][32][32].

#define B_   32
#define NI   2048
#define NO   64
#define DO_  32
#define DI   16
#define IC   16                  // i's per wave
#define WSTRIDE ((size_t)NO * DO_ * DI)   // elements to next i in W/Wb

typedef __bf16 bf16x8 __attribute__((ext_vector_type(8)));
typedef float  f32x16 __attribute__((ext_vector_type(16)));
union U16B { uint4 u; bf16x8 v; };

// ---------------- x fp32 -> bf16 ----------------
__global__ __launch_bounds__(256) void convert_x_kernel(const float* __restrict__ x,
                                                        __bf16* __restrict__ xb)
{
    const int idx = (blockIdx.x * 256 + threadIdx.x) * 4;   // 1M floats total
    const float4 f = *(const float4*)(x + idx);
    __bf16 o[4] = {(__bf16)f.x, (__bf16)f.y, (__bf16)f.z, (__bf16)f.w};
    *(uint2*)(xb + idx) = *(uint2*)o;
}

// ---------------- pass A: convert W + s0 partial (c uniform; scaled later) ----------------
__global__ __launch_bounds__(256) void passA_kernel(const float* __restrict__ W,
                                                    const __bf16* __restrict__ xb,
                                                    __bf16* __restrict__ Wb,
                                                    float* __restrict__ part)
{
    __shared__ float lds[4][1024];
    const int tid = threadIdx.x, lane = tid & 63, w = tid >> 6;
    const int j  = blockIdx.x & 63;
    const int ch = blockIdx.x >> 6;          // 0..31
    const int i0 = ch * 64 + w * IC;
    const int m  = lane & 31, h = lane >> 5;

    const size_t toff = (((size_t)i0 * NO + j) * DO_ + m) * DI + 8 * h;
    const float*  Wp  = W  + toff;
    __bf16*       Wbp = Wb + toff;
    const __bf16* xp  = xb + ((size_t)m * NI + i0) * DI + 8 * h;

    f32x16 acc;
    #pragma unroll
    for (int r = 0; r < 16; ++r) acc[r] = 0.0f;

    #pragma unroll 4
    for (int ii = 0; ii < IC; ++ii) {
        const float4 w0 = ((const float4*)Wp)[0];
        const float4 w1 = ((const float4*)Wp)[1];
        U16B a;
        a.v[0] = (__bf16)w0.x; a.v[1] = (__bf16)w0.y; a.v[2] = (__bf16)w0.z; a.v[3] = (__bf16)w0.w;
        a.v[4] = (__bf16)w1.x; a.v[5] = (__bf16)w1.y; a.v[6] = (__bf16)w1.z; a.v[7] = (__bf16)w1.w;
        *(uint4*)Wbp = a.u;
        U16B b; b.u = *(const uint4*)xp;
        acc = __builtin_amdgcn_mfma_f32_32x32x16_bf16(a.v, b.v, acc, 0, 0, 0);
        Wp += WSTRIDE; Wbp += WSTRIDE; xp += DI;
    }

    #pragma unroll
    for (int r = 0; r < 16; ++r) {
        const int row = (r & 3) + 8 * (r >> 2) + 4 * h;
        lds[w][row * 32 + m] = acc[r];
    }
    __syncthreads();
    float* pb = part + ((size_t)ch * NO + j) * 1024;
    #pragma unroll
    for (int q = 0; q < 4; ++q) {
        const int idx = tid + 256 * q;
        pb[idx] = lds[0][idx] + lds[1][idx] + lds[2][idx] + lds[3][idx];
    }
}

// ---------------- s-pass: partials of sum_i c*u_hat ----------------
__global__ __launch_bounds__(256) void s_kernel(const __bf16* __restrict__ Wb,
                                                const __bf16* __restrict__ xb,
                                                const float* __restrict__ c,
                                                float* __restrict__ part)
{
    __shared__ float lds[4][1024];
    const int tid = threadIdx.x, lane = tid & 63, w = tid >> 6;
    const int j  = blockIdx.x & 63;
    const int ch = blockIdx.x >> 6;
    const int i0 = ch * 64 + w * IC;
    const int m  = lane & 31, h = lane >> 5;

    const __bf16* Wp = Wb + (((size_t)i0 * NO + j) * DO_ + m) * DI + 8 * h;
    const __bf16* xp = xb + ((size_t)m * NI + i0) * DI + 8 * h;
    const float*  cp = c  + (size_t)i0 * (NO * B_) + j * B_ + m;

    f32x16 acc;
    #pragma unroll
    for (int r = 0; r < 16; ++r) acc[r] = 0.0f;

    #pragma unroll 4
    for (int ii = 0; ii < IC; ++ii) {
        U16B a; a.u = *(const uint4*)Wp;
        U16B b; b.u = *(const uint4*)xp;
        const float cv = *cp;
        f32x16 z;
        #pragma unroll
        for (int r = 0; r < 16; ++r) z[r] = 0.0f;
        f32x16 u = __builtin_amdgcn_mfma_f32_32x32x16_bf16(a.v, b.v, z, 0, 0, 0);
        #pragma unroll
        for (int r = 0; r < 16; ++r) acc[r] = fmaf(cv, u[r], acc[r]);
        Wp += WSTRIDE; xp += DI; cp += NO * B_;
    }

    #pragma unroll
    for (int r = 0; r < 16; ++r) {
        const int row = (r & 3) + 8 * (r >> 2) + 4 * h;
        lds[w][row * 32 + m] = acc[r];
    }
    __syncthreads();
    float* pb = part + ((size_t)ch * NO + j) * 1024;
    #pragma unroll
    for (int q = 0; q < 4; ++q) {
        const int idx = tid + 256 * q;
        pb[idx] = lds[0][idx] + lds[1][idx] + lds[2][idx] + lds[3][idx];
    }
}

// ---------------- t-pass: t[i][j][b] = sum_d u_hat[d][b] * vT[j][d][b] ----------------
__global__ __launch_bounds__(256) void t_kernel(const __bf16* __restrict__ Wb,
                                                const __bf16* __restrict__ xb,
                                                const float* __restrict__ vT,
                                                float* __restrict__ t)
{
    const int tid = threadIdx.x, lane = tid & 63;
    const int wid = blockIdx.x * 4 + (tid >> 6);   // 0..8191
    const int j   = wid & 63;
    const int i0  = (wid >> 6) * IC;
    const int m   = lane & 31, h = lane >> 5;

    const __bf16* Wp = Wb + (((size_t)i0 * NO + j) * DO_ + m) * DI + 8 * h;
    const __bf16* xp = xb + ((size_t)m * NI + i0) * DI + 8 * h;

    float vr[16];
    #pragma unroll
    for (int r = 0; r < 16; ++r) {
        const int row = (r & 3) + 8 * (r >> 2) + 4 * h;
        vr[r] = vT[((size_t)j * DO_ + row) * B_ + m];
    }

    #pragma unroll 4
    for (int ii = 0; ii < IC; ++ii) {
        U16B a; a.u = *(const uint4*)Wp;
        U16B b; b.u = *(const uint4*)xp;
        f32x16 z;
        #pragma unroll
        for (int r = 0; r < 16; ++r) z[r] = 0.0f;
        f32x16 u = __builtin_amdgcn_mfma_f32_32x32x16_bf16(a.v, b.v, z, 0, 0, 0);

        float p0 = 0.f, p1 = 0.f, p2 = 0.f, p3 = 0.f;
        #pragma unroll
        for (int r = 0; r < 16; r += 4) {
            p0 = fmaf(u[r + 0], vr[r + 0], p0);
            p1 = fmaf(u[r + 1], vr[r + 1], p1);
            p2 = fmaf(u[r + 2], vr[r + 2], p2);
            p3 = fmaf(u[r + 3], vr[r + 3], p3);
        }
        float tp = (p0 + p1) + (p2 + p3);
        tp += __shfl_xor(tp, 32);
        if (h == 0) t[(size_t)(i0 + ii) * (NO * B_) + j * B_ + m] = tp;
        Wp += WSTRIDE; xp += DI;
    }
}

// ---------------- softmax over j per (i,b), in place ----------------
__global__ __launch_bounds__(256) void softmax_kernel(float* __restrict__ t)
{
    __shared__ float red[8][32];
    __shared__ float row_m[32];
    __shared__ float row_s[32];
    const int i = blockIdx.x;
    const int tid = threadIdx.x;
    const int b = tid & 31;
    const int g = tid >> 5;
    float* base = t + (size_t)i * (NO * B_);

    float tv[8];
    #pragma unroll
    for (int k = 0; k < 8; ++k) tv[k] = base[(g * 8 + k) * B_ + b];

    float m8 = tv[0];
    #pragma unroll
    for (int k = 1; k < 8; ++k) m8 = fmaxf(m8, tv[k]);
    red[g][b] = m8;
    __syncthreads();
    if (tid < 32) {
        float mm = red[0][tid];
        #pragma unroll
        for (int gg = 1; gg < 8; ++gg) mm = fmaxf(mm, red[gg][tid]);
        row_m[tid] = mm;
    }
    __syncthreads();
    const float mm = row_m[b];
    float e[8]; float ps = 0.f;
    #pragma unroll
    for (int k = 0; k < 8; ++k) { e[k] = __expf(tv[k] - mm); ps += e[k]; }
    __syncthreads();
    red[g][b] = ps;
    __syncthreads();
    if (tid < 32) {
        float ss = 0.f;
        #pragma unroll
        for (int gg = 0; gg < 8; ++gg) ss += red[gg][tid];
        row_s[tid] = 1.0f / ss;
    }
    __syncthreads();
    const float inv = row_s[b];
    #pragma unroll
    for (int k = 0; k < 8; ++k) base[(g * 8 + k) * B_ + b] = e[k] * inv;
}

// ---------------- squash (+ partial reduction over 32 chunks) ----------------
// mode 0: out[j][d][b] = v        mode 1: out[j][d][b] = v0T + v       mode 2: out[b][j][d] = v
__global__ __launch_bounds__(256) void squash_kernel(const float* __restrict__ part,
                                                     const float* __restrict__ bias,
                                                     const float* __restrict__ v0T,
                                                     float* __restrict__ out,
                                                     int mode, float prescale)
{
    __shared__ float red[8][32];
    __shared__ float scl[32];
    const int j = blockIdx.x;
    const int tid = threadIdx.x;
    const int b = tid & 31;
    const int g = tid >> 5;
    const int d0 = g * 4;

    float sv[4];
    #pragma unroll
    for (int q = 0; q < 4; ++q) {
        const float* p = part + (size_t)j * 1024 + (d0 + q) * 32 + b;
        float a = 0.f;
        #pragma unroll
        for (int ch = 0; ch < 32; ++ch) a += p[(size_t)ch * NO * 1024];
        sv[q] = a * prescale + bias[j * DO_ + d0 + q];
    }

    float p2s = 0.f;
    #pragma unroll
    for (int q = 0; q < 4; ++q) p2s = fmaf(sv[q], sv[q], p2s);
    red[g][b] = p2s;
    __syncthreads();
    if (tid < 32) {
        float n2 = 0.f;
        #pragma unroll
        for (int gg = 0; gg < 8; ++gg) n2 += red[gg][tid];
        scl[tid] = n2 / ((1.0f + n2) * sqrtf(n2 + 1e-7f));
    }
    __syncthreads();
    const float sc = scl[b];
    #pragma unroll
    for (int q = 0; q < 4; ++q) {
        const int d = d0 + q;
        const float vq = sv[q] * sc;
        if (mode == 0)      out[((size_t)j * DO_ + d) * B_ + b] = vq;
        else if (mode == 1) out[((size_t)j * DO_ + d) * B_ + b] =
                                v0T[((size_t)j * DO_ + d) * B_ + b] + vq;
        else                out[((size_t)b * NO + j) * DO_ + d] = vq;
    }
}

extern "C" void kernel_launch(void* const* d_in, const int* in_sizes, int n_in,
                              void* d_out, int out_size, void* d_ws, size_t ws_size,
                              hipStream_t stream)
{
    const float* x    = (const float*)d_in[0];   // [32][2048][16]
    const float* W    = (const float*)d_in[1];   // [2048][64][32][16]
    const float* bias = (const float*)d_in[2];   // [64][32]
    float* out = (float*)d_out;                  // [32][64][32]

    char* ws = (char*)d_ws;
    __bf16* Wb   = (__bf16*)ws;                                  // 128 MB
    __bf16* xb   = (__bf16*)(ws + (size_t)134217728);            // 2 MB
    float*  t_buf= (float*) (ws + (size_t)134217728 + 2097152);  // 16 MB
    float*  part = (float*) (ws + (size_t)134217728 + 2097152 + 16777216); // 8 MB
    float*  v0T  = (float*) (ws + (size_t)134217728 + 2097152 + 16777216 + 8388608);
    float*  vsT  = v0T + (size_t)NO * DO_ * B_;

    const dim3 tW(256);
    const dim3 gX(1024), gP(2048), gSm(NI), gSq(NO);

    convert_x_kernel<<<gX, tW, 0, stream>>>(x, xb);

    // ---- iter 0: pass A (convert W + s0 with uniform c folded as prescale)
    passA_kernel<<<gP, tW, 0, stream>>>(W, xb, Wb, part);
    squash_kernel<<<gSq, tW, 0, stream>>>(part, bias, nullptr, v0T, 0, 1.0f / 64.0f);

    // ---- iter 1
    t_kernel<<<gP, tW, 0, stream>>>(Wb, xb, v0T, t_buf);
    softmax_kernel<<<gSm, tW, 0, stream>>>(t_buf);
    s_kernel<<<gP, tW, 0, stream>>>(Wb, xb, t_buf, part);
    squash_kernel<<<gSq, tW, 0, stream>>>(part, bias, v0T, vsT, 1, 1.0f);

    // ---- iter 2
    t_kernel<<<gP, tW, 0, stream>>>(Wb, xb, vsT, t_buf);
    softmax_kernel<<<gSm, tW, 0, stream>>>(t_buf);
    s_kernel<<<gP, tW, 0, stream>>>(Wb, xb, t_buf, part);
    squash_kernel<<<gSq, tW, 0, stream>>>(part, bias, nullptr, out, 2, 1.0f);
}

// Round 3
// 519.435 us; speedup vs baseline: 1.2204x; 1.0457x over previous
//
#include <hip/hip_runtime.h>

// RoutingCapsule: B=32, N_in=2048, N_out=64, D_out=32, D_in=16
// R3: same 5-sweep structure as R2, plus xT pre-transpose so the MFMA
// B-fragment load is a single coalesced 1KB wave read instead of a
// 32-cache-line gather (was in every iteration of every W-sweep).
//   convert_xT: x fp32 [b][i][p] -> xT bf16 [i][lane][8p]   (2 MB)
//   pass A:     stream W fp32; write Wb bf16 + s0 partials (uniform c)
//   t-pass x2:  logits t[i][j][b] (streams Wb) ; softmax x2 in-place
//   s-pass x2:  s partials = sum_i c*u_hat (c post-MFMA FMA)
//   squash x3 reduces partials [32ch][64j][32d][32b] and squashes.

#define B_   32
#define NI   2048
#define NO   64
#define DO_  32
#define DI   16
#define IC   16
#define WSTRIDE ((size_t)NO * DO_ * DI)

typedef __bf16 bf16x8 __attribute__((ext_vector_type(8)));
typedef float  f32x16 __attribute__((ext_vector_type(16)));
union U16B { uint4 u; bf16x8 v; };

// ---------------- x -> xT bf16 in exact B-fragment order ----------------
// xT[((i*2+h)*32+m)*8 + e] = x[m][i][8h+e];  lane l=(h*32+m) reads 16B at i*1024+l*16.
__global__ __launch_bounds__(256) void convert_xT_kernel(const float* __restrict__ x,
                                                         __bf16* __restrict__ xT)
{
    const int idx = blockIdx.x * 256 + threadIdx.x;   // 131072 = 2048*2*32
    const int m = idx & 31;
    const int h = (idx >> 5) & 1;
    const int i = idx >> 6;
    const float4 f0 = *(const float4*)(x + ((size_t)m * NI + i) * DI + 8 * h);
    const float4 f1 = *(const float4*)(x + ((size_t)m * NI + i) * DI + 8 * h + 4);
    __bf16 o[8] = {(__bf16)f0.x, (__bf16)f0.y, (__bf16)f0.z, (__bf16)f0.w,
                   (__bf16)f1.x, (__bf16)f1.y, (__bf16)f1.z, (__bf16)f1.w};
    *(uint4*)(xT + (size_t)idx * 8) = *(uint4*)o;
}

// ---------------- pass A: convert W + s0 partials ----------------
__global__ __launch_bounds__(256) void passA_kernel(const float* __restrict__ W,
                                                    const __bf16* __restrict__ xT,
                                                    __bf16* __restrict__ Wb,
                                                    float* __restrict__ part)
{
    __shared__ float lds[4][1024];
    const int tid = threadIdx.x, lane = tid & 63, w = tid >> 6;
    const int j  = blockIdx.x & 63;
    const int ch = blockIdx.x >> 6;
    const int i0 = ch * 64 + w * IC;
    const int m  = lane & 31, h = lane >> 5;

    const size_t toff = (((size_t)i0 * NO + j) * DO_ + m) * DI + 8 * h;
    const float*  Wp  = W  + toff;
    __bf16*       Wbp = Wb + toff;
    const __bf16* xp  = xT + (size_t)i0 * 512 + lane * 8;

    f32x16 acc;
    #pragma unroll
    for (int r = 0; r < 16; ++r) acc[r] = 0.0f;

    #pragma unroll 4
    for (int ii = 0; ii < IC; ++ii) {
        const float4 w0 = ((const float4*)Wp)[0];
        const float4 w1 = ((const float4*)Wp)[1];
        U16B a;
        a.v[0] = (__bf16)w0.x; a.v[1] = (__bf16)w0.y; a.v[2] = (__bf16)w0.z; a.v[3] = (__bf16)w0.w;
        a.v[4] = (__bf16)w1.x; a.v[5] = (__bf16)w1.y; a.v[6] = (__bf16)w1.z; a.v[7] = (__bf16)w1.w;
        *(uint4*)Wbp = a.u;
        U16B b; b.u = *(const uint4*)xp;
        acc = __builtin_amdgcn_mfma_f32_32x32x16_bf16(a.v, b.v, acc, 0, 0, 0);
        Wp += WSTRIDE; Wbp += WSTRIDE; xp += 512;
    }

    #pragma unroll
    for (int r = 0; r < 16; ++r) {
        const int row = (r & 3) + 8 * (r >> 2) + 4 * h;
        lds[w][row * 32 + m] = acc[r];
    }
    __syncthreads();
    float* pb = part + ((size_t)ch * NO + j) * 1024;
    #pragma unroll
    for (int q = 0; q < 4; ++q) {
        const int idx = tid + 256 * q;
        pb[idx] = lds[0][idx] + lds[1][idx] + lds[2][idx] + lds[3][idx];
    }
}

// ---------------- s-pass ----------------
__global__ __launch_bounds__(256) void s_kernel(const __bf16* __restrict__ Wb,
                                                const __bf16* __restrict__ xT,
                                                const float* __restrict__ c,
                                                float* __restrict__ part)
{
    __shared__ float lds[4][1024];
    const int tid = threadIdx.x, lane = tid & 63, w = tid >> 6;
    const int j  = blockIdx.x & 63;
    const int ch = blockIdx.x >> 6;
    const int i0 = ch * 64 + w * IC;
    const int m  = lane & 31, h = lane >> 5;

    const __bf16* Wp = Wb + (((size_t)i0 * NO + j) * DO_ + m) * DI + 8 * h;
    const __bf16* xp = xT + (size_t)i0 * 512 + lane * 8;
    const float*  cp = c  + (size_t)i0 * (NO * B_) + j * B_ + m;

    f32x16 acc;
    #pragma unroll
    for (int r = 0; r < 16; ++r) acc[r] = 0.0f;

    #pragma unroll 4
    for (int ii = 0; ii < IC; ++ii) {
        U16B a; a.u = *(const uint4*)Wp;
        U16B b; b.u = *(const uint4*)xp;
        const float cv = *cp;
        f32x16 z;
        #pragma unroll
        for (int r = 0; r < 16; ++r) z[r] = 0.0f;
        f32x16 u = __builtin_amdgcn_mfma_f32_32x32x16_bf16(a.v, b.v, z, 0, 0, 0);
        #pragma unroll
        for (int r = 0; r < 16; ++r) acc[r] = fmaf(cv, u[r], acc[r]);
        Wp += WSTRIDE; xp += 512; cp += NO * B_;
    }

    #pragma unroll
    for (int r = 0; r < 16; ++r) {
        const int row = (r & 3) + 8 * (r >> 2) + 4 * h;
        lds[w][row * 32 + m] = acc[r];
    }
    __syncthreads();
    float* pb = part + ((size_t)ch * NO + j) * 1024;
    #pragma unroll
    for (int q = 0; q < 4; ++q) {
        const int idx = tid + 256 * q;
        pb[idx] = lds[0][idx] + lds[1][idx] + lds[2][idx] + lds[3][idx];
    }
}

// ---------------- t-pass ----------------
__global__ __launch_bounds__(256) void t_kernel(const __bf16* __restrict__ Wb,
                                                const __bf16* __restrict__ xT,
                                                const float* __restrict__ vT,
                                                float* __restrict__ t)
{
    const int tid = threadIdx.x, lane = tid & 63;
    const int wid = blockIdx.x * 4 + (tid >> 6);
    const int j   = wid & 63;
    const int i0  = (wid >> 6) * IC;
    const int m   = lane & 31, h = lane >> 5;

    const __bf16* Wp = Wb + (((size_t)i0 * NO + j) * DO_ + m) * DI + 8 * h;
    const __bf16* xp = xT + (size_t)i0 * 512 + lane * 8;

    float vr[16];
    #pragma unroll
    for (int r = 0; r < 16; ++r) {
        const int row = (r & 3) + 8 * (r >> 2) + 4 * h;
        vr[r] = vT[((size_t)j * DO_ + row) * B_ + m];
    }

    #pragma unroll 4
    for (int ii = 0; ii < IC; ++ii) {
        U16B a; a.u = *(const uint4*)Wp;
        U16B b; b.u = *(const uint4*)xp;
        f32x16 z;
        #pragma unroll
        for (int r = 0; r < 16; ++r) z[r] = 0.0f;
        f32x16 u = __builtin_amdgcn_mfma_f32_32x32x16_bf16(a.v, b.v, z, 0, 0, 0);

        float p0 = 0.f, p1 = 0.f, p2 = 0.f, p3 = 0.f;
        #pragma unroll
        for (int r = 0; r < 16; r += 4) {
            p0 = fmaf(u[r + 0], vr[r + 0], p0);
            p1 = fmaf(u[r + 1], vr[r + 1], p1);
            p2 = fmaf(u[r + 2], vr[r + 2], p2);
            p3 = fmaf(u[r + 3], vr[r + 3], p3);
        }
        float tp = (p0 + p1) + (p2 + p3);
        tp += __shfl_xor(tp, 32);
        if (h == 0) t[(size_t)(i0 + ii) * (NO * B_) + j * B_ + m] = tp;
        Wp += WSTRIDE; xp += 512;
    }
}

// ---------------- softmax over j per (i,b), in place ----------------
__global__ __launch_bounds__(256) void softmax_kernel(float* __restrict__ t)
{
    __shared__ float red[8][32];
    __shared__ float row_m[32];
    __shared__ float row_s[32];
    const int i = blockIdx.x;
    const int tid = threadIdx.x;
    const int b = tid & 31;
    const int g = tid >> 5;
    float* base = t + (size_t)i * (NO * B_);

    float tv[8];
    #pragma unroll
    for (int k = 0; k < 8; ++k) tv[k] = base[(g * 8 + k) * B_ + b];

    float m8 = tv[0];
    #pragma unroll
    for (int k = 1; k < 8; ++k) m8 = fmaxf(m8, tv[k]);
    red[g][b] = m8;
    __syncthreads();
    if (tid < 32) {
        float mm = red[0][tid];
        #pragma unroll
        for (int gg = 1; gg < 8; ++gg) mm = fmaxf(mm, red[gg][tid]);
        row_m[tid] = mm;
    }
    __syncthreads();
    const float mm = row_m[b];
    float e[8]; float ps = 0.f;
    #pragma unroll
    for (int k = 0; k < 8; ++k) { e[k] = __expf(tv[k] - mm); ps += e[k]; }
    __syncthreads();
    red[g][b] = ps;
    __syncthreads();
    if (tid < 32) {
        float ss = 0.f;
        #pragma unroll
        for (int gg = 0; gg < 8; ++gg) ss += red[gg][tid];
        row_s[tid] = 1.0f / ss;
    }
    __syncthreads();
    const float inv = row_s[b];
    #pragma unroll
    for (int k = 0; k < 8; ++k) base[(g * 8 + k) * B_ + b] = e[k] * inv;
}

// ---------------- squash (+ chunk reduction) ----------------
__global__ __launch_bounds__(256) void squash_kernel(const float* __restrict__ part,
                                                     const float* __restrict__ bias,
                                                     const float* __restrict__ v0T,
                                                     float* __restrict__ out,
                                                     int mode, float prescale)
{
    __shared__ float red[8][32];
    __shared__ float scl[32];
    const int j = blockIdx.x;
    const int tid = threadIdx.x;
    const int b = tid & 31;
    const int g = tid >> 5;
    const int d0 = g * 4;

    float sv[4];
    #pragma unroll
    for (int q = 0; q < 4; ++q) {
        const float* p = part + (size_t)j * 1024 + (d0 + q) * 32 + b;
        float a = 0.f;
        #pragma unroll
        for (int ch = 0; ch < 32; ++ch) a += p[(size_t)ch * NO * 1024];
        sv[q] = a * prescale + bias[j * DO_ + d0 + q];
    }

    float p2s = 0.f;
    #pragma unroll
    for (int q = 0; q < 4; ++q) p2s = fmaf(sv[q], sv[q], p2s);
    red[g][b] = p2s;
    __syncthreads();
    if (tid < 32) {
        float n2 = 0.f;
        #pragma unroll
        for (int gg = 0; gg < 8; ++gg) n2 += red[gg][tid];
        scl[tid] = n2 / ((1.0f + n2) * sqrtf(n2 + 1e-7f));
    }
    __syncthreads();
    const float sc = scl[b];
    #pragma unroll
    for (int q = 0; q < 4; ++q) {
        const int d = d0 + q;
        const float vq = sv[q] * sc;
        if (mode == 0)      out[((size_t)j * DO_ + d) * B_ + b] = vq;
        else if (mode == 1) out[((size_t)j * DO_ + d) * B_ + b] =
                                v0T[((size_t)j * DO_ + d) * B_ + b] + vq;
        else                out[((size_t)b * NO + j) * DO_ + d] = vq;
    }
}

extern "C" void kernel_launch(void* const* d_in, const int* in_sizes, int n_in,
                              void* d_out, int out_size, void* d_ws, size_t ws_size,
                              hipStream_t stream)
{
    const float* x    = (const float*)d_in[0];
    const float* W    = (const float*)d_in[1];
    const float* bias = (const float*)d_in[2];
    float* out = (float*)d_out;

    char* ws = (char*)d_ws;
    __bf16* Wb   = (__bf16*)ws;                                   // 128 MB
    __bf16* xT   = (__bf16*)(ws + (size_t)134217728);             // 2 MB
    float*  t_buf= (float*) (ws + (size_t)134217728 + 2097152);   // 16 MB
    float*  part = (float*) (ws + (size_t)134217728 + 2097152 + 16777216); // 8 MB
    float*  v0T  = (float*) (ws + (size_t)134217728 + 2097152 + 16777216 + 8388608);
    float*  vsT  = v0T + (size_t)NO * DO_ * B_;

    const dim3 tW(256);
    const dim3 gX(512), gP(2048), gSm(NI), gSq(NO);

    convert_xT_kernel<<<gX, tW, 0, stream>>>(x, xT);

    passA_kernel<<<gP, tW, 0, stream>>>(W, xT, Wb, part);
    squash_kernel<<<gSq, tW, 0, stream>>>(part, bias, nullptr, v0T, 0, 1.0f / 64.0f);

    t_kernel<<<gP, tW, 0, stream>>>(Wb, xT, v0T, t_buf);
    softmax_kernel<<<gSm, tW, 0, stream>>>(t_buf);
    s_kernel<<<gP, tW, 0, stream>>>(Wb, xT, t_buf, part);
    squash_kernel<<<gSq, tW, 0, stream>>>(part, bias, v0T, vsT, 1, 1.0f);

    t_kernel<<<gP, tW, 0, stream>>>(Wb, xT, vsT, t_buf);
    softmax_kernel<<<gSm, tW, 0, stream>>>(t_buf);
    s_kernel<<<gP, tW, 0, stream>>>(Wb, xT, t_buf, part);
    squash_kernel<<<gSq, tW, 0, stream>>>(part, bias, nullptr, out, 2, 1.0f);
}